// Round 1
// 449.756 us; speedup vs baseline: 1.0131x; 1.0131x over previous
//
#include <hip/hip_runtime.h>
#include <stdint.h>

#define B_SZ 16
#define L_SEQ 8192
#define D_MOD 512
#define N_H 8
#define D_H 64
#define KSEL 100
#define HSUB 16
#define HSTRIDE 258  // 258 mod 32 == 2 -> the 16 sub-hists put the same digit on 16 distinct banks

// ---------------------------------------------------------------------------
// Fully fused kernel: one block per (batch, head), 512 threads (8 waves).
//   phase 0: query row + w bit patterns -> LDS; EARLY-ISSUE Wq,Wk register
//            prefetch (overlaps the 32KB w stage)
//   phase 1: Qh = Wq_h @ query + bq_h                  (wave-per-row, prefetched Wq)
//   phase 2: a = Qh @ Wk_h (wave-split over d, prefetched Wk, LDS partial reduce)
//   phase 3: exact top-100 radix select; histogram uses 16 bank-staggered
//            sub-histograms to kill same-address LDS-atomic serialization
//            (uniform [0,1) floats concentrate ~50% of lanes in exponent bin 0x3F)
//   phase 4: ONE software-pipelined gather pass over the 100 landmark rows with
//            exp2-domain online softmax; Wv/Wo prefetch issued under this loop
//   phase 5: cross-wave softmax combine -> y; attn_h = Wv_h @ y + bv_h (prefetched Wv)
//   phase 6: out partial: atomicAdd(Wo[:,h*64:+64] @ attn_h (+bo if h==0)) (prefetched Wo)
// d_out is zeroed via hipMemsetAsync before launch.
// Landmark set is permutation-invariant downstream (softmax-weighted sum);
// ties take lowest index (jax-stable). exp2(x*log2e) == exp(x) exactly in math,
// ~1ulp numerically -> well inside tolerance (prev absmax 1.2e-4).
// ---------------------------------------------------------------------------
__global__ __launch_bounds__(512) void fused_attn_kernel(
    const float* __restrict__ mamba, const float* __restrict__ skip,
    const float* __restrict__ w,
    const float* __restrict__ Wq, const float* __restrict__ bq,
    const float* __restrict__ Wk, const float* __restrict__ bk,
    const float* __restrict__ Wv, const float* __restrict__ bv,
    const float* __restrict__ Wo, const float* __restrict__ bo,
    float* __restrict__ out) {
    const int b = blockIdx.x >> 3;
    const int h = blockIdx.x & 7;
    const int t = threadIdx.x;
    const int lane = t & 63;
    const int wave = t >> 6;  // 0..7
    const int sub = t >> 5;   // 0..15 (half-wave id for split histograms)

    __shared__ uint32_t uval[L_SEQ];        // 32 KB
    __shared__ float s_part[8 * D_MOD];     // 16 KB (a-partials, then pv-partials)
    __shared__ int hist16[HSUB][HSTRIDE];   // 16.1 KB bank-staggered sub-histograms
    __shared__ float s_query[D_MOD];
    __shared__ float s_a[D_MOD];
    __shared__ float s_y[D_MOD];
    __shared__ float s_Qh[D_H];
    __shared__ float s_ah[D_H];
    __shared__ int s_idx[128];
    __shared__ int s_eq[128];
    __shared__ int s_wtot[4];
    __shared__ float s_m[8], s_l[8];
    __shared__ uint32_t s_thresh;
    __shared__ int s_rem, s_cnt, s_ecnt;
    __shared__ float s_qdotbk;

    if (t == 0) { s_cnt = 0; s_ecnt = 0; }  // hoisted: saves a barrier later

    // ---- phase 0: loads (query+Wq+Wk issued first; they gate phases 1-2) ----
    const float* qrow = mamba + ((size_t)b * L_SEQ + (L_SEQ - 1)) * D_MOD;
    s_query[t] = qrow[t];

    const float* Wqh = Wq + (size_t)(h * D_H) * D_MOD;
    const float* Wkh = Wk + (size_t)(h * D_H) * D_MOD;
    float4 qw[8][2], kw[8][2];  // early-issue register prefetch (128 VGPRs)
    #pragma unroll
    for (int r = 0; r < 8; ++r) {  // phase-1 mapping: d = wave + r*8
        const float4* row4 = (const float4*)(Wqh + (size_t)(wave + r * 8) * D_MOD);
        qw[r][0] = row4[lane * 2]; qw[r][1] = row4[lane * 2 + 1];
    }
    #pragma unroll
    for (int dd = 0; dd < 8; ++dd) {  // phase-2 mapping: d = wave*8 + dd
        const float4* row4 = (const float4*)(Wkh + (size_t)(wave * 8 + dd) * D_MOD);
        kw[dd][0] = row4[lane * 2]; kw[dd][1] = row4[lane * 2 + 1];
    }
    {   // w bit patterns -> LDS, 16B per lane per iteration (4 iters)
        const uint4* wb4 = (const uint4*)(w + (size_t)b * L_SEQ);
        uint4* uv4 = (uint4*)uval;
        #pragma unroll
        for (int i = 0; i < 4; ++i) uv4[t + i * 512] = wb4[t + i * 512];
    }
    __syncthreads();

    // ---- phase 1: Qh (wave-per-row, prefetched Wq) ----
    {
        const float4* q4 = (const float4*)s_query;
        float4 q0 = q4[lane * 2], q1 = q4[lane * 2 + 1];
        #pragma unroll
        for (int r = 0; r < 8; ++r) {
            float sum = qw[r][0].x * q0.x + qw[r][0].y * q0.y + qw[r][0].z * q0.z +
                        qw[r][0].w * q0.w + qw[r][1].x * q1.x + qw[r][1].y * q1.y +
                        qw[r][1].z * q1.z + qw[r][1].w * q1.w;
            #pragma unroll
            for (int off = 32; off > 0; off >>= 1) sum += __shfl_down(sum, off);
            if (lane == 0) s_Qh[wave + r * 8] = sum + bq[h * D_H + wave + r * 8];
        }
    }
    __syncthreads();

    // ---- phase 2: a[c] = sum_d Qh[d]*Wk_h[d,c], wave-split over d (prefetched Wk) ----
    if (wave == 0) {  // fold bk: qdotbk = Qh . bk_h
        float v = s_Qh[lane] * bk[h * D_H + lane];
        #pragma unroll
        for (int off = 32; off > 0; off >>= 1) v += __shfl_down(v, off);
        if (lane == 0) s_qdotbk = v;
    }
    {
        float4 a0 = {0, 0, 0, 0}, a1 = {0, 0, 0, 0};
        #pragma unroll
        for (int dd = 0; dd < 8; ++dd) {
            float qd = s_Qh[wave * 8 + dd];
            a0.x += qd * kw[dd][0].x; a0.y += qd * kw[dd][0].y;
            a0.z += qd * kw[dd][0].z; a0.w += qd * kw[dd][0].w;
            a1.x += qd * kw[dd][1].x; a1.y += qd * kw[dd][1].y;
            a1.z += qd * kw[dd][1].z; a1.w += qd * kw[dd][1].w;
        }
        float4* p4 = (float4*)&s_part[wave * D_MOD + lane * 8];
        p4[0] = a0; p4[1] = a1;
    }
    __syncthreads();
    {
        float v = 0.f;
        #pragma unroll
        for (int ww = 0; ww < 8; ++ww) v += s_part[ww * D_MOD + t];
        s_a[t] = v;
    }

    // ---- phase 3: radix select top-100 (split histograms, 4 barriers/pass) ----
    uint32_t prefix = 0, pmask = 0;
    int remaining = KSEL;
    for (int pass = 0; pass < 4; ++pass) {
        const int shift = 24 - 8 * pass;
        for (int i = t; i < HSUB * HSTRIDE; i += 512) ((int*)hist16)[i] = 0;
        __syncthreads();
        for (int i = t; i < L_SEQ; i += 512) {
            uint32_t u = uval[i];
            if ((u & pmask) == prefix) atomicAdd(&hist16[sub][(u >> shift) & 0xFF], 1);
        }
        __syncthreads();
        int binCount = 0, v = 0;
        if (t < 256) {
            #pragma unroll
            for (int s = 0; s < HSUB; ++s) binCount += hist16[s][t];
            v = binCount;
            #pragma unroll
            for (int off = 1; off < 64; off <<= 1) {
                int u = __shfl_down(v, off);
                if (lane + off < 64) v += u;
            }
            if (lane == 0) s_wtot[wave] = v;  // wave in 0..3 here
        }
        __syncthreads();
        if (t < 256) {
            int hi = 0;
            for (int w2 = wave + 1; w2 < 4; ++w2) hi += s_wtot[w2];
            int suff = v + hi;                // # elems in bins >= t (matching prefix)
            int suff_next = suff - binCount;  // # elems in bins > t
            if (suff >= remaining && suff_next < remaining) {
                s_thresh = prefix | ((uint32_t)t << shift);
                s_rem = remaining - suff_next;
            }
        }
        __syncthreads();
        prefix = s_thresh;
        remaining = s_rem;
        pmask |= (uint32_t)0xFF << shift;
        // no trailing barrier needed: next write to s_thresh is 3 barriers away,
        // and next-pass zeroing only touches hist16 (last read before this barrier)
    }

    // collect > threshold, and equal-to-threshold candidates
    for (int i = t; i < L_SEQ; i += 512) {
        uint32_t u = uval[i];
        if (u > prefix) {
            int p = atomicAdd(&s_cnt, 1);
            s_idx[p] = i;
        } else if (u == prefix) {
            int p = atomicAdd(&s_ecnt, 1);
            if (p < 128) s_eq[p] = i;
        }
    }
    __syncthreads();
    const int cntgt = s_cnt;  // == KSEL - remaining
    if (wave == 0) {  // take `remaining` lowest-index ties via shfl-min extraction
        int n = s_ecnt < 128 ? s_ecnt : 128;
        int taken_val = -1;
        for (int r = 0; r < remaining; ++r) {
            int mymin = 0x7FFFFFFF;
            for (int i = lane; i < n; i += 64) {
                int e = s_eq[i];
                if (e > taken_val && e < mymin) mymin = e;
            }
            #pragma unroll
            for (int off = 32; off > 0; off >>= 1) {
                int o = __shfl_xor(mymin, off);
                mymin = o < mymin ? o : mymin;
            }
            if (lane == 0) s_idx[cntgt + r] = mymin;
            taken_val = mymin;  // butterfly leaves min on all lanes
        }
    }
    __syncthreads();

    // ---- phase 4: software-pipelined gather with exp2-domain online softmax ----
    const float scale_l2e = 0.125f * 1.44269504088896340736f;  // (1/sqrt(64))*log2(e)
    const float* Wvh = Wv + (size_t)(h * D_H) * D_MOD;
    float4 vw[8][2];  // Wv prefetch (issued under the gather loop)
    float4 ow[16];    // Wo slice prefetch
    {
        const float4* a4 = (const float4*)s_a;
        float4 av0 = a4[lane * 2], av1 = a4[lane * 2 + 1];
        float qdotbk = s_qdotbk;
        float m = -INFINITY, l = 0.f;
        float4 acc0 = {0, 0, 0, 0}, acc1 = {0, 0, 0, 0};
        int j = wave;
        float4 x0 = {0, 0, 0, 0}, x1 = {0, 0, 0, 0};
        if (j < KSEL) {  // critical-path row first
            const float4* x4 =
                (const float4*)(skip + ((size_t)b * L_SEQ + s_idx[j]) * D_MOD);
            x0 = x4[lane * 2]; x1 = x4[lane * 2 + 1];
        }
        // issue phase-5/6 weight loads now; they complete under the gather loop
        #pragma unroll
        for (int r = 0; r < 8; ++r) {  // phase-5 mapping: d = wave + r*8
            const float4* row4 = (const float4*)(Wvh + (size_t)(wave + r * 8) * D_MOD);
            vw[r][0] = row4[lane * 2]; vw[r][1] = row4[lane * 2 + 1];
        }
        {
            const float4* wrow = (const float4*)(Wo + (size_t)t * D_MOD + h * D_H);
            #pragma unroll
            for (int i = 0; i < 16; ++i) ow[i] = wrow[i];
        }
        while (j < KSEL) {
            const int jn = j + 8;
            float4 n0 = {0, 0, 0, 0}, n1 = {0, 0, 0, 0};
            if (jn < KSEL) {  // prefetch next row while reducing current
                const float4* x4 =
                    (const float4*)(skip + ((size_t)b * L_SEQ + s_idx[jn]) * D_MOD);
                n0 = x4[lane * 2]; n1 = x4[lane * 2 + 1];
            }
            float sum = x0.x * av0.x + x0.y * av0.y + x0.z * av0.z + x0.w * av0.w +
                        x1.x * av1.x + x1.y * av1.y + x1.z * av1.z + x1.w * av1.w;
            #pragma unroll
            for (int off = 32; off > 0; off >>= 1) sum += __shfl_xor(sum, off);
            float s = (sum + qdotbk) * scale_l2e;  // log2 domain
            float mnew = fmaxf(m, s);
            float c = exp2f(m - mnew);  // 0 on first iter (m = -inf); bare v_exp_f32
            float e = exp2f(s - mnew);
            l = l * c + e;
            acc0.x = acc0.x * c + e * x0.x; acc0.y = acc0.y * c + e * x0.y;
            acc0.z = acc0.z * c + e * x0.z; acc0.w = acc0.w * c + e * x0.w;
            acc1.x = acc1.x * c + e * x1.x; acc1.y = acc1.y * c + e * x1.y;
            acc1.z = acc1.z * c + e * x1.z; acc1.w = acc1.w * c + e * x1.w;
            m = mnew;
            x0 = n0; x1 = n1;
            j = jn;
        }
        float4* p4 = (float4*)&s_part[wave * D_MOD + lane * 8];
        p4[0] = acc0; p4[1] = acc1;
        if (lane == 0) { s_m[wave] = m; s_l[wave] = l; }
    }
    __syncthreads();

    // ---- phase 5: cross-wave combine -> y, then attn_h = Wv_h @ y + bv_h ----
    {
        float mstar = -INFINITY;
        #pragma unroll
        for (int ww = 0; ww < 8; ++ww) mstar = fmaxf(mstar, s_m[ww]);
        float num = 0.f, den = 0.f;
        #pragma unroll
        for (int ww = 0; ww < 8; ++ww) {
            float sc = exp2f(s_m[ww] - mstar);  // log2 domain
            num += sc * s_part[ww * D_MOD + t];
            den += sc * s_l[ww];
        }
        s_y[t] = num / den;
    }
    __syncthreads();

    {
        const float4* y4 = (const float4*)s_y;
        float4 y0 = y4[lane * 2], y1 = y4[lane * 2 + 1];
        #pragma unroll
        for (int r = 0; r < 8; ++r) {
            float sum = vw[r][0].x * y0.x + vw[r][0].y * y0.y + vw[r][0].z * y0.z +
                        vw[r][0].w * y0.w + vw[r][1].x * y1.x + vw[r][1].y * y1.y +
                        vw[r][1].z * y1.z + vw[r][1].w * y1.w;
            #pragma unroll
            for (int off = 32; off > 0; off >>= 1) sum += __shfl_down(sum, off);
            if (lane == 0) s_ah[wave + r * 8] = sum + bv[h * D_H + wave + r * 8];
        }
    }
    __syncthreads();

    // ---- phase 6: out partial = Wo[:, h*64:(h+1)*64] @ attn_h, atomicAdd ----
    {
        const float4* ah4 = (const float4*)s_ah;
        float acc = 0.f;
        #pragma unroll
        for (int i = 0; i < 16; ++i) {
            float4 wv = ow[i];
            float4 av = ah4[i];
            acc += wv.x * av.x + wv.y * av.y + wv.z * av.z + wv.w * av.w;
        }
        if (h == 0) acc += bo[t];
        atomicAdd(&out[(size_t)b * D_MOD + t], acc);
    }
}

extern "C" void kernel_launch(void* const* d_in, const int* in_sizes, int n_in,
                              void* d_out, int out_size, void* d_ws, size_t ws_size,
                              hipStream_t stream) {
    const float* mamba = (const float*)d_in[0];
    const float* skip  = (const float*)d_in[1];
    const float* hw    = (const float*)d_in[2];
    const float* Wq    = (const float*)d_in[3];
    const float* bq    = (const float*)d_in[4];
    const float* Wk    = (const float*)d_in[5];
    const float* bk    = (const float*)d_in[6];
    const float* Wv    = (const float*)d_in[7];
    const float* bv    = (const float*)d_in[8];
    const float* Wo    = (const float*)d_in[9];
    const float* bo    = (const float*)d_in[10];
    float* out = (float*)d_out;

    hipMemsetAsync(out, 0, (size_t)out_size * sizeof(float), stream);
    fused_attn_kernel<<<B_SZ * N_H, 512, 0, stream>>>(mamba, skip, hw, Wq, bq,
                                                      Wk, bk, Wv, bv, Wo, bo, out);
}

// Round 2
// 440.079 us; speedup vs baseline: 1.0353x; 1.0220x over previous
//
#include <hip/hip_runtime.h>
#include <stdint.h>

#define B_SZ 16
#define L_SEQ 8192
#define D_MOD 512
#define N_H 8
#define D_H 64
#define KSEL 100
#define NW 16        // waves per block (1024 threads)
#define HSUB 16
#define HSTRIDE 258  // 258 mod 32 == 2 -> the 16 sub-hists put the same digit on 16 distinct banks

// ---------------------------------------------------------------------------
// Fully fused kernel: one block per (batch, head), 1024 threads (16 waves).
// 16 waves = 4 waves/SIMD (vs 2 before): halves every serial per-block term
// and doubles latency hiding. Phases:
//   phase 0: query row + w bit patterns -> LDS; early-issue Wq,Wk reg prefetch
//   phase 1: Qh = Wq_h @ query + bq_h                  (4 rows/wave)
//   phase 2: a = Qh @ Wk_h (4 d/wave, LDS partial reduce over 16 waves)
//   phase 3: exact top-100 radix select; 16 bank-staggered sub-histograms
//            (uniform [0,1) floats concentrate ~50% of lanes in one exponent bin)
//   phase 4: software-pipelined gather over 100 landmark rows, 16-wave split
//            (7 online-softmax steps max vs 13), exp2-domain; Wv/Wo prefetch
//            issued under this loop
//   phase 5: cross-wave softmax combine -> y; attn_h = Wv_h @ y + bv_h
//   phase 6: out partial: each output elem split across 2 threads (half-dots),
//            both atomicAdd into out (+bo once on half 0 of h==0)
// d_out is zeroed via hipMemsetAsync before launch.
// Landmark set is permutation-invariant downstream (softmax-weighted sum);
// ties take lowest index (jax-stable).
// ---------------------------------------------------------------------------
__global__ __launch_bounds__(1024) void fused_attn_kernel(
    const float* __restrict__ mamba, const float* __restrict__ skip,
    const float* __restrict__ w,
    const float* __restrict__ Wq, const float* __restrict__ bq,
    const float* __restrict__ Wk, const float* __restrict__ bk,
    const float* __restrict__ Wv, const float* __restrict__ bv,
    const float* __restrict__ Wo, const float* __restrict__ bo,
    float* __restrict__ out) {
    const int b = blockIdx.x >> 3;
    const int h = blockIdx.x & 7;
    const int t = threadIdx.x;
    const int lane = t & 63;
    const int wave = t >> 6;        // 0..15
    const int sub = (t >> 5) & 15;  // sub-histogram id

    __shared__ uint32_t uval[L_SEQ];              // 32 KB
    __shared__ float s_part[NW * D_MOD];          // 32 KB (a-partials, then pv-partials)
    __shared__ int hist16[HSUB][HSTRIDE];         // 16.1 KB bank-staggered sub-histograms
    __shared__ __align__(16) float s_query[D_MOD];
    __shared__ __align__(16) float s_a[D_MOD];
    __shared__ __align__(16) float s_y[D_MOD];
    __shared__ __align__(16) float s_Qh[D_H];
    __shared__ __align__(16) float s_ah[D_H];
    __shared__ int s_idx[128];
    __shared__ int s_eq[128];
    __shared__ int s_wtot[4];
    __shared__ float s_m[NW], s_l[NW];
    __shared__ uint32_t s_thresh;
    __shared__ int s_rem, s_cnt, s_ecnt;
    __shared__ float s_qdotbk;

    if (t == 0) { s_cnt = 0; s_ecnt = 0; }  // hoisted: saves a barrier later

    // ---- phase 0: loads (query+Wq+Wk issued first; they gate phases 1-2) ----
    const float* qrow = mamba + ((size_t)b * L_SEQ + (L_SEQ - 1)) * D_MOD;
    if (t < D_MOD) s_query[t] = qrow[t];

    const float* Wqh = Wq + (size_t)(h * D_H) * D_MOD;
    const float* Wkh = Wk + (size_t)(h * D_H) * D_MOD;
    float4 qw[4][2], kw[4][2];  // early-issue register prefetch (64 VGPRs)
    #pragma unroll
    for (int r = 0; r < 4; ++r) {  // phase-1 mapping: d = wave + r*16
        const float4* row4 = (const float4*)(Wqh + (size_t)(wave + r * 16) * D_MOD);
        qw[r][0] = row4[lane * 2]; qw[r][1] = row4[lane * 2 + 1];
    }
    #pragma unroll
    for (int dd = 0; dd < 4; ++dd) {  // phase-2 mapping: d = wave*4 + dd
        const float4* row4 = (const float4*)(Wkh + (size_t)(wave * 4 + dd) * D_MOD);
        kw[dd][0] = row4[lane * 2]; kw[dd][1] = row4[lane * 2 + 1];
    }
    {   // w bit patterns -> LDS, 16B per lane per iteration (2 iters)
        const uint4* wb4 = (const uint4*)(w + (size_t)b * L_SEQ);
        uint4* uv4 = (uint4*)uval;
        #pragma unroll
        for (int i = 0; i < 2; ++i) uv4[t + i * 1024] = wb4[t + i * 1024];
    }
    __syncthreads();

    // ---- phase 1: Qh (4 rows per wave, prefetched Wq) ----
    {
        const float4* q4 = (const float4*)s_query;
        float4 q0 = q4[lane * 2], q1 = q4[lane * 2 + 1];
        #pragma unroll
        for (int r = 0; r < 4; ++r) {
            float sum = qw[r][0].x * q0.x + qw[r][0].y * q0.y + qw[r][0].z * q0.z +
                        qw[r][0].w * q0.w + qw[r][1].x * q1.x + qw[r][1].y * q1.y +
                        qw[r][1].z * q1.z + qw[r][1].w * q1.w;
            #pragma unroll
            for (int off = 32; off > 0; off >>= 1) sum += __shfl_down(sum, off);
            if (lane == 0) s_Qh[wave + r * 16] = sum + bq[h * D_H + wave + r * 16];
        }
    }
    __syncthreads();

    // ---- phase 2: a[c] = sum_d Qh[d]*Wk_h[d,c], 4 d per wave (prefetched Wk) ----
    if (wave == 0) {  // fold bk: qdotbk = Qh . bk_h
        float v = s_Qh[lane] * bk[h * D_H + lane];
        #pragma unroll
        for (int off = 32; off > 0; off >>= 1) v += __shfl_down(v, off);
        if (lane == 0) s_qdotbk = v;
    }
    {
        float4 a0 = {0, 0, 0, 0}, a1 = {0, 0, 0, 0};
        #pragma unroll
        for (int dd = 0; dd < 4; ++dd) {
            float qd = s_Qh[wave * 4 + dd];
            a0.x += qd * kw[dd][0].x; a0.y += qd * kw[dd][0].y;
            a0.z += qd * kw[dd][0].z; a0.w += qd * kw[dd][0].w;
            a1.x += qd * kw[dd][1].x; a1.y += qd * kw[dd][1].y;
            a1.z += qd * kw[dd][1].z; a1.w += qd * kw[dd][1].w;
        }
        float4* p4 = (float4*)&s_part[wave * D_MOD + lane * 8];
        p4[0] = a0; p4[1] = a1;
    }
    __syncthreads();
    if (t < D_MOD) {
        float v = 0.f;
        #pragma unroll
        for (int ww = 0; ww < NW; ++ww) v += s_part[ww * D_MOD + t];
        s_a[t] = v;
    }

    // ---- phase 3: radix select top-100 (split histograms, 8-iter scans) ----
    uint32_t prefix = 0, pmask = 0;
    int remaining = KSEL;
    for (int pass = 0; pass < 4; ++pass) {
        const int shift = 24 - 8 * pass;
        for (int i = t; i < HSUB * HSTRIDE; i += 1024) ((int*)hist16)[i] = 0;
        __syncthreads();
        for (int i = t; i < L_SEQ; i += 1024) {
            uint32_t u = uval[i];
            if ((u & pmask) == prefix) atomicAdd(&hist16[sub][(u >> shift) & 0xFF], 1);
        }
        __syncthreads();
        int binCount = 0, v = 0;
        if (t < 256) {
            #pragma unroll
            for (int s = 0; s < HSUB; ++s) binCount += hist16[s][t];
            v = binCount;
            #pragma unroll
            for (int off = 1; off < 64; off <<= 1) {
                int u = __shfl_down(v, off);
                if (lane + off < 64) v += u;
            }
            if (lane == 0) s_wtot[wave] = v;  // wave in 0..3 here
        }
        __syncthreads();
        if (t < 256) {
            int hi = 0;
            for (int w2 = wave + 1; w2 < 4; ++w2) hi += s_wtot[w2];
            int suff = v + hi;                // # elems in bins >= t (matching prefix)
            int suff_next = suff - binCount;  // # elems in bins > t
            if (suff >= remaining && suff_next < remaining) {
                s_thresh = prefix | ((uint32_t)t << shift);
                s_rem = remaining - suff_next;
            }
        }
        __syncthreads();
        prefix = s_thresh;
        remaining = s_rem;
        pmask |= (uint32_t)0xFF << shift;
        // no trailing barrier needed: next write to s_thresh is 3 barriers away,
        // and next-pass zeroing only touches hist16 (last read before this barrier)
    }

    // collect > threshold, and equal-to-threshold candidates
    for (int i = t; i < L_SEQ; i += 1024) {
        uint32_t u = uval[i];
        if (u > prefix) {
            int p = atomicAdd(&s_cnt, 1);
            s_idx[p] = i;
        } else if (u == prefix) {
            int p = atomicAdd(&s_ecnt, 1);
            if (p < 128) s_eq[p] = i;
        }
    }
    __syncthreads();
    const int cntgt = s_cnt;  // == KSEL - remaining
    if (wave == 0) {  // take `remaining` lowest-index ties via shfl-min extraction
        int n = s_ecnt < 128 ? s_ecnt : 128;
        int taken_val = -1;
        for (int r = 0; r < remaining; ++r) {
            int mymin = 0x7FFFFFFF;
            for (int i = lane; i < n; i += 64) {
                int e = s_eq[i];
                if (e > taken_val && e < mymin) mymin = e;
            }
            #pragma unroll
            for (int off = 32; off > 0; off >>= 1) {
                int o = __shfl_xor(mymin, off);
                mymin = o < mymin ? o : mymin;
            }
            if (lane == 0) s_idx[cntgt + r] = mymin;
            taken_val = mymin;  // butterfly leaves min on all lanes
        }
    }
    __syncthreads();

    // ---- phase 4: software-pipelined gather with exp2-domain online softmax ----
    const float scale_l2e = 0.125f * 1.44269504088896340736f;  // (1/sqrt(64))*log2(e)
    const float* Wvh = Wv + (size_t)(h * D_H) * D_MOD;
    float4 vw[4][2];  // Wv prefetch (issued under the gather loop)
    float4 ow[8];     // Wo half-slice prefetch (each out elem split across 2 threads)
    {
        const float4* a4 = (const float4*)s_a;
        float4 av0 = a4[lane * 2], av1 = a4[lane * 2 + 1];
        float qdotbk = s_qdotbk;
        float m = -INFINITY, l = 0.f;
        float4 acc0 = {0, 0, 0, 0}, acc1 = {0, 0, 0, 0};
        int j = wave;
        float4 x0, x1;
        {   // j = wave < 100 always: critical-path row first
            const float4* x4 =
                (const float4*)(skip + ((size_t)b * L_SEQ + s_idx[j]) * D_MOD);
            x0 = x4[lane * 2]; x1 = x4[lane * 2 + 1];
        }
        // issue phase-5/6 weight loads now; they complete under the gather loop
        #pragma unroll
        for (int r = 0; r < 4; ++r) {  // phase-5 mapping: d = wave + r*16
            const float4* row4 = (const float4*)(Wvh + (size_t)(wave + r * 16) * D_MOD);
            vw[r][0] = row4[lane * 2]; vw[r][1] = row4[lane * 2 + 1];
        }
        {
            const float4* wrow = (const float4*)(Wo + (size_t)(t & 511) * D_MOD +
                                                 h * D_H + (t >> 9) * 32);
            #pragma unroll
            for (int i = 0; i < 8; ++i) ow[i] = wrow[i];
        }
        while (j < KSEL) {
            const int jn = j + NW;
            float4 n0 = {0, 0, 0, 0}, n1 = {0, 0, 0, 0};
            if (jn < KSEL) {  // prefetch next row while reducing current
                const float4* x4 =
                    (const float4*)(skip + ((size_t)b * L_SEQ + s_idx[jn]) * D_MOD);
                n0 = x4[lane * 2]; n1 = x4[lane * 2 + 1];
            }
            float sum = x0.x * av0.x + x0.y * av0.y + x0.z * av0.z + x0.w * av0.w +
                        x1.x * av1.x + x1.y * av1.y + x1.z * av1.z + x1.w * av1.w;
            #pragma unroll
            for (int off = 32; off > 0; off >>= 1) sum += __shfl_xor(sum, off);
            float s = (sum + qdotbk) * scale_l2e;  // log2 domain
            float mnew = fmaxf(m, s);
            float c = exp2f(m - mnew);  // 0 on first iter (m = -inf); bare v_exp_f32
            float e = exp2f(s - mnew);
            l = l * c + e;
            acc0.x = acc0.x * c + e * x0.x; acc0.y = acc0.y * c + e * x0.y;
            acc0.z = acc0.z * c + e * x0.z; acc0.w = acc0.w * c + e * x0.w;
            acc1.x = acc1.x * c + e * x1.x; acc1.y = acc1.y * c + e * x1.y;
            acc1.z = acc1.z * c + e * x1.z; acc1.w = acc1.w * c + e * x1.w;
            m = mnew;
            x0 = n0; x1 = n1;
            j = jn;
        }
        float4* p4 = (float4*)&s_part[wave * D_MOD + lane * 8];
        p4[0] = acc0; p4[1] = acc1;
        if (lane == 0) { s_m[wave] = m; s_l[wave] = l; }
    }
    __syncthreads();

    // ---- phase 5: cross-wave combine -> y, then attn_h = Wv_h @ y + bv_h ----
    if (t < D_MOD) {
        float mstar = -INFINITY;
        #pragma unroll
        for (int ww = 0; ww < NW; ++ww) mstar = fmaxf(mstar, s_m[ww]);
        float num = 0.f, den = 0.f;
        #pragma unroll
        for (int ww = 0; ww < NW; ++ww) {
            float sc = exp2f(s_m[ww] - mstar);  // log2 domain
            num += sc * s_part[ww * D_MOD + t];
            den += sc * s_l[ww];
        }
        s_y[t] = num / den;
    }
    __syncthreads();

    {
        const float4* y4 = (const float4*)s_y;
        float4 y0 = y4[lane * 2], y1 = y4[lane * 2 + 1];
        #pragma unroll
        for (int r = 0; r < 4; ++r) {
            float sum = vw[r][0].x * y0.x + vw[r][0].y * y0.y + vw[r][0].z * y0.z +
                        vw[r][0].w * y0.w + vw[r][1].x * y1.x + vw[r][1].y * y1.y +
                        vw[r][1].z * y1.z + vw[r][1].w * y1.w;
            #pragma unroll
            for (int off = 32; off > 0; off >>= 1) sum += __shfl_down(sum, off);
            if (lane == 0) s_ah[wave + r * 16] = sum + bv[h * D_H + wave + r * 16];
        }
    }
    __syncthreads();

    // ---- phase 6: out[c] partial = Wo[c, h*64+half*32 : +32] @ attn_h[half*32:+32]
    //      (each output element split across 2 threads; both atomicAdd) ----
    {
        const float4* ah4 = (const float4*)(s_ah + (t >> 9) * 32);
        float acc = 0.f;
        #pragma unroll
        for (int i = 0; i < 8; ++i) {
            float4 wv = ow[i];
            float4 av = ah4[i];
            acc += wv.x * av.x + wv.y * av.y + wv.z * av.z + wv.w * av.w;
        }
        if (h == 0 && t < D_MOD) acc += bo[t];
        atomicAdd(&out[(size_t)b * D_MOD + (t & 511)], acc);
    }
}

extern "C" void kernel_launch(void* const* d_in, const int* in_sizes, int n_in,
                              void* d_out, int out_size, void* d_ws, size_t ws_size,
                              hipStream_t stream) {
    const float* mamba = (const float*)d_in[0];
    const float* skip  = (const float*)d_in[1];
    const float* hw    = (const float*)d_in[2];
    const float* Wq    = (const float*)d_in[3];
    const float* bq    = (const float*)d_in[4];
    const float* Wk    = (const float*)d_in[5];
    const float* bk    = (const float*)d_in[6];
    const float* Wv    = (const float*)d_in[7];
    const float* bv    = (const float*)d_in[8];
    const float* Wo    = (const float*)d_in[9];
    const float* bo    = (const float*)d_in[10];
    float* out = (float*)d_out;

    hipMemsetAsync(out, 0, (size_t)out_size * sizeof(float), stream);
    fused_attn_kernel<<<B_SZ * N_H, 1024, 0, stream>>>(mamba, skip, hw, Wq, bq,
                                                       Wk, bk, Wv, bv, Wo, bo, out);
}